// Round 3
// baseline (12769.601 us; speedup 1.0000x reference)
//
#include <hip/hip_runtime.h>

#define Hdim 200
#define NP   800
#define Tlen 100
#define BT   32          // batch rows per WG
#define KB   7           // K blocks of 32 (200 -> 224 padded)
#define HS   232         // padded h row stride (ushorts): 2-way LDS bank aliasing = free
#define NT   50          // 800/16 gate-col tiles (M dimension of Z^T)
#define THREADS 640      // 10 waves x 5 M-tiles each
#define CTPW 5
#define MATSZ (KB*NT*64*8)   // 179200 ushorts per packed matrix

typedef float f32x4 __attribute__((ext_vector_type(4)));
typedef short s16x8 __attribute__((ext_vector_type(8)));

__device__ __forceinline__ ushort f2bf(float f) {
    unsigned u = __float_as_uint(f);
    return (ushort)((u + 0x7fffu + ((u >> 16) & 1u)) >> 16);   // RTNE
}
__device__ __forceinline__ float bf2f(ushort s) {
    return __uint_as_float(((unsigned)s) << 16);
}
__device__ __forceinline__ float sigmoid_fast(float v) {
    return 1.0f / (1.0f + __expf(-v));
}
__device__ __forceinline__ float tanh_fast(float v) {
    return 2.0f / (1.0f + __expf(-2.0f * v)) - 1.0f;
}

// ---- pack 5 recurrent matrices [200][800] fp32 -> bf16 fragment layout ----
// slot (mi, kb, tile, lane, j) = W[k = kb*32 + (lane>>4)*8 + j][n' = tile*16 + (lane&15)]
// gate-interleaved cols: n' = unit*4 + gate -> src col = gate*200 + unit. k>=200 -> 0.
// Same bytes serve A-operand layout A[m=l15][k=q*8+j] for the transposed GEMM.
__global__ void pack_weights(const float* __restrict__ U0, const float* __restrict__ W1,
                             const float* __restrict__ U1, const float* __restrict__ W2,
                             const float* __restrict__ U2, ushort* __restrict__ dst) {
    int idx = blockIdx.x * blockDim.x + threadIdx.x;
    if (idx >= 5 * KB * NT * 64) return;
    int lane = idx & 63; int rest = idx >> 6;
    int nt = rest % NT; rest /= NT;
    int kb = rest % KB; int mi = rest / KB;
    const float* src = (mi == 0) ? U0 : (mi == 1) ? W1 : (mi == 2) ? U1 : (mi == 3) ? W2 : U2;
    int np = nt * 16 + (lane & 15);
    int ncol = (np & 3) * Hdim + (np >> 2);          // gate*200 + unit
    int k0 = kb * 32 + (lane >> 4) * 8;
    ushort v[8];
#pragma unroll
    for (int j = 0; j < 8; ++j) {
        int k = k0 + j;
        v[j] = (k < Hdim) ? f2bf(src[k * NP + ncol]) : (ushort)0;
    }
    uint4 o;
    o.x = (unsigned)v[0] | ((unsigned)v[1] << 16);
    o.y = (unsigned)v[2] | ((unsigned)v[3] << 16);
    o.z = (unsigned)v[4] | ((unsigned)v[5] << 16);
    o.w = (unsigned)v[6] | ((unsigned)v[7] << 16);
    ((uint4*)dst)[idx] = o;
}

// Z^T pass: acc[nt][mt] += A(weights, global) @ B(h rows, LDS), K=224
// C tile: row = gate-col (m), col = batch (n).
__device__ __forceinline__ void gemm_pass(f32x4 (&acc)[2][CTPW],
                                          const ushort* __restrict__ hrow,
                                          const ushort* __restrict__ bmat,
                                          int lane, int ct0) {
    const int l15 = lane & 15, q = lane >> 4;
    const ushort* b0p = hrow + l15 * HS + q * 8;          // batch rows 0..15
    const ushort* b1p = hrow + (16 + l15) * HS + q * 8;   // batch rows 16..31
    const ushort* ap = bmat + (size_t)(ct0 * 64 + lane) * 8;
    for (int kb = 0; kb < KB; ++kb) {
        s16x8 bh0 = *(const s16x8*)(b0p + kb * 32);
        s16x8 bh1 = *(const s16x8*)(b1p + kb * 32);
        const ushort* ak = ap + (size_t)kb * (NT * 64 * 8);
#pragma unroll
        for (int mt = 0; mt < CTPW; ++mt) {
            s16x8 af = *(const s16x8*)(ak + mt * 64 * 8);
            acc[0][mt] = __builtin_amdgcn_mfma_f32_16x16x32_bf16(af, bh0, acc[0][mt], 0, 0, 0);
            acc[1][mt] = __builtin_amdgcn_mfma_f32_16x16x32_bf16(af, bh1, acc[1][mt], 0, 0, 0);
        }
    }
}

// lane-local cell update: acc[nt][mt] regs r=0..3 are gates i,f,g,o of
// unit u=(ct0+mt)*4+q, batch n=nt*16+l15. No shuffles. Writes new h (bf16).
__device__ __forceinline__ void gate_phase(f32x4 (&acc)[2][CTPW],
                                           float (&creg)[2][CTPW],
                                           ushort (*hbl)[HS],
                                           int lane, int ct0) {
    const int l15 = lane & 15, q = lane >> 4;
#pragma unroll
    for (int nt = 0; nt < 2; ++nt) {
#pragma unroll
        for (int mt = 0; mt < CTPW; ++mt) {
            const int u = (ct0 + mt) * 4 + q;
            const int n = nt * 16 + l15;
            f32x4 z = acc[nt][mt];
            float iv = sigmoid_fast(z[0]);
            float fv = sigmoid_fast(z[1]);
            float gv = tanh_fast(z[2]);
            float ov = sigmoid_fast(z[3]);
            float c = fv * creg[nt][mt] + iv * gv;
            creg[nt][mt] = c;
            hbl[n][u] = f2bf(ov * tanh_fast(c));
        }
    }
}

__global__ void __launch_bounds__(THREADS, 5)
lstm3_mfma(const float* __restrict__ x,
           const float* __restrict__ W0, const float* __restrict__ b0,
           const float* __restrict__ b1, const float* __restrict__ b2,
           const float* __restrict__ Wfc, const float* __restrict__ bfc,
           const ushort* __restrict__ packed,
           float* __restrict__ out) {
    __shared__ ushort hb[3][BT][HS];   // h state, bf16, rows = batch (44.5 KB)
    __shared__ float  xT[Tlen][BT];    // x transposed (12.8 KB)
    __shared__ float  pbw[4][NP];      // permuted b0,b1,b2,W0 (12.8 KB)

    const int tid = threadIdx.x;
    const int wave = tid >> 6, lane = tid & 63;
    const int l15 = lane & 15, q = lane >> 4;
    const int ct0 = wave * CTPW;       // M-tile base
    const int bbase = blockIdx.x * BT;

    for (int i = tid; i < 3 * BT * HS; i += THREADS) ((ushort*)hb)[i] = 0;
    for (int i = tid; i < BT * Tlen; i += THREADS) {
        int m = i / Tlen, t = i % Tlen;
        xT[t][m] = x[(size_t)(bbase + m) * Tlen + t];
    }
    for (int i = tid; i < NP; i += THREADS) {
        int nc = (i & 3) * Hdim + (i >> 2);   // permuted col -> src col
        pbw[0][i] = b0[nc]; pbw[1][i] = b1[nc]; pbw[2][i] = b2[nc]; pbw[3][i] = W0[nc];
    }
    __syncthreads();

    float creg[3][2][CTPW];   // c state: 30 regs, static (layer, nt, mt) mapping
#pragma unroll
    for (int l = 0; l < 3; ++l)
#pragma unroll
        for (int nt = 0; nt < 2; ++nt)
#pragma unroll
            for (int mt = 0; mt < CTPW; ++mt) creg[l][nt][mt] = 0.0f;

    const ushort* pU0 = packed;
    const ushort* pW1 = packed + (size_t)MATSZ;
    const ushort* pU1 = packed + (size_t)2 * MATSZ;
    const ushort* pW2 = packed + (size_t)3 * MATSZ;
    const ushort* pU2 = packed + (size_t)4 * MATSZ;

    for (int t = 0; t < Tlen; ++t) {
        f32x4 acc[2][CTPW];

        // ---- layer 0: Z^T = b0 + W0^T x_t + U0^T h0 ----
        const float xn0 = xT[t][l15];
        const float xn1 = xT[t][16 + l15];
#pragma unroll
        for (int mt = 0; mt < CTPW; ++mt) {
            const int row = (ct0 + mt) * 16 + q * 4;
            float4 bb = *(const float4*)&pbw[0][row];
            float4 ww = *(const float4*)&pbw[3][row];
            acc[0][mt][0] = fmaf(xn0, ww.x, bb.x); acc[1][mt][0] = fmaf(xn1, ww.x, bb.x);
            acc[0][mt][1] = fmaf(xn0, ww.y, bb.y); acc[1][mt][1] = fmaf(xn1, ww.y, bb.y);
            acc[0][mt][2] = fmaf(xn0, ww.z, bb.z); acc[1][mt][2] = fmaf(xn1, ww.z, bb.z);
            acc[0][mt][3] = fmaf(xn0, ww.w, bb.w); acc[1][mt][3] = fmaf(xn1, ww.w, bb.w);
        }
        gemm_pass(acc, &hb[0][0][0], pU0, lane, ct0);
        __syncthreads();                               // all reads of old h0 done
        gate_phase(acc, creg[0], hb[0], lane, ct0);    // write new h0
        __syncthreads();

        // ---- layer 1: Z^T = b1 + W1^T h0new + U1^T h1 ----
#pragma unroll
        for (int mt = 0; mt < CTPW; ++mt) {
            const int row = (ct0 + mt) * 16 + q * 4;
            float4 bb = *(const float4*)&pbw[1][row];
#pragma unroll
            for (int r = 0; r < 4; ++r) {
                float v = (r == 0) ? bb.x : (r == 1) ? bb.y : (r == 2) ? bb.z : bb.w;
                acc[0][mt][r] = v; acc[1][mt][r] = v;
            }
        }
        gemm_pass(acc, &hb[0][0][0], pW1, lane, ct0);
        gemm_pass(acc, &hb[1][0][0], pU1, lane, ct0);
        __syncthreads();
        gate_phase(acc, creg[1], hb[1], lane, ct0);
        __syncthreads();

        // ---- layer 2: Z^T = b2 + W2^T h1new + U2^T h2 ----
#pragma unroll
        for (int mt = 0; mt < CTPW; ++mt) {
            const int row = (ct0 + mt) * 16 + q * 4;
            float4 bb = *(const float4*)&pbw[2][row];
#pragma unroll
            for (int r = 0; r < 4; ++r) {
                float v = (r == 0) ? bb.x : (r == 1) ? bb.y : (r == 2) ? bb.z : bb.w;
                acc[0][mt][r] = v; acc[1][mt][r] = v;
            }
        }
        gemm_pass(acc, &hb[1][0][0], pW2, lane, ct0);
        gemm_pass(acc, &hb[2][0][0], pU2, lane, ct0);
        __syncthreads();
        gate_phase(acc, creg[2], hb[2], lane, ct0);
        __syncthreads();
    }

    // ---- dense head: y = tanh(h2 @ Wfc + bfc); contiguous float4 stores ----
    for (int gidx = tid; gidx < BT * 100; gidx += THREADS) {
        int m = gidx / 100;
        int j4 = (gidx % 100) * 4;
        const ushort* h2 = &hb[2][m][0];
        float4 a4 = *(const float4*)(bfc + j4);
        float s0 = a4.x, s1 = a4.y, s2 = a4.z, s3 = a4.w;
        for (int k = 0; k < Hdim; ++k) {
            float hk = bf2f(h2[k]);
            float4 w4 = *(const float4*)(Wfc + (size_t)k * 400 + j4);
            s0 = fmaf(hk, w4.x, s0);
            s1 = fmaf(hk, w4.y, s1);
            s2 = fmaf(hk, w4.z, s2);
            s3 = fmaf(hk, w4.w, s3);
        }
        float4 o4;
        o4.x = tanh_fast(s0); o4.y = tanh_fast(s1);
        o4.z = tanh_fast(s2); o4.w = tanh_fast(s3);
        *(float4*)(out + (size_t)(bbase + m) * 400 + j4) = o4;
    }
}

extern "C" void kernel_launch(void* const* d_in, const int* in_sizes, int n_in,
                              void* d_out, int out_size, void* d_ws, size_t ws_size,
                              hipStream_t stream) {
    const float* x   = (const float*)d_in[0];
    const float* W0  = (const float*)d_in[1];
    const float* U0  = (const float*)d_in[2];
    const float* b0  = (const float*)d_in[3];
    const float* W1  = (const float*)d_in[4];
    const float* U1  = (const float*)d_in[5];
    const float* b1  = (const float*)d_in[6];
    const float* W2  = (const float*)d_in[7];
    const float* U2  = (const float*)d_in[8];
    const float* b2  = (const float*)d_in[9];
    const float* Wfc = (const float*)d_in[10];
    const float* bfc = (const float*)d_in[11];
    float* out = (float*)d_out;
    ushort* packed = (ushort*)d_ws;

    const int B = in_sizes[0] / Tlen;   // 8192
    const int pack_threads = 5 * KB * NT * 64;
    pack_weights<<<(pack_threads + 255) / 256, 256, 0, stream>>>(U0, W1, U1, W2, U2, packed);
    lstm3_mfma<<<B / BT, THREADS, 0, stream>>>(x, W0, b0, b1, b2, Wfc, bfc, packed, out);
}

// Round 4
// 9865.043 us; speedup vs baseline: 1.2944x; 1.2944x over previous
//
#include <hip/hip_runtime.h>

#define Hdim 200
#define NP   800
#define Tlen 100
#define BT   32          // batch rows per WG -> grid = 256 = 1 WG/CU
#define KB   7           // K blocks of 32 (200 -> 224 padded)
#define HS   232         // padded h row stride (ushorts): 2-way LDS bank aliasing = free
#define NT   50          // 800/16 gate-col tiles (M dimension of Z^T)
#define THREADS 640      // 10 waves x 5 M-tiles each
#define CTPW 5
#define MATSZ (KB*NT*64*8)   // 179200 ushorts per packed matrix

typedef float f32x4 __attribute__((ext_vector_type(4)));
typedef short s16x8 __attribute__((ext_vector_type(8)));

__device__ __forceinline__ ushort f2bf(float f) {
    unsigned u = __float_as_uint(f);
    return (ushort)((u + 0x7fffu + ((u >> 16) & 1u)) >> 16);   // RTNE
}
__device__ __forceinline__ float bf2f(ushort s) {
    return __uint_as_float(((unsigned)s) << 16);
}
__device__ __forceinline__ float sigmoid_fast(float v) {
    return 1.0f / (1.0f + __expf(-v));
}
__device__ __forceinline__ float tanh_fast(float v) {
    return 2.0f / (1.0f + __expf(-2.0f * v)) - 1.0f;
}

// ---- pack 5 recurrent matrices [200][800] fp32 -> bf16 fragment layout ----
// slot (mi, kb, tile, lane, j) = W[k = kb*32 + (lane>>4)*8 + j][n' = tile*16 + (lane&15)]
// gate-interleaved cols: n' = unit*4 + gate -> src col = gate*200 + unit. k>=200 -> 0.
__global__ void pack_weights(const float* __restrict__ U0, const float* __restrict__ W1,
                             const float* __restrict__ U1, const float* __restrict__ W2,
                             const float* __restrict__ U2, ushort* __restrict__ dst) {
    int idx = blockIdx.x * blockDim.x + threadIdx.x;
    if (idx >= 5 * KB * NT * 64) return;
    int lane = idx & 63; int rest = idx >> 6;
    int nt = rest % NT; rest /= NT;
    int kb = rest % KB; int mi = rest / KB;
    const float* src = (mi == 0) ? U0 : (mi == 1) ? W1 : (mi == 2) ? U1 : (mi == 3) ? W2 : U2;
    int np = nt * 16 + (lane & 15);
    int ncol = (np & 3) * Hdim + (np >> 2);          // gate*200 + unit
    int k0 = kb * 32 + (lane >> 4) * 8;
    ushort v[8];
#pragma unroll
    for (int j = 0; j < 8; ++j) {
        int k = k0 + j;
        v[j] = (k < Hdim) ? f2bf(src[k * NP + ncol]) : (ushort)0;
    }
    uint4 o;
    o.x = (unsigned)v[0] | ((unsigned)v[1] << 16);
    o.y = (unsigned)v[2] | ((unsigned)v[3] << 16);
    o.z = (unsigned)v[4] | ((unsigned)v[5] << 16);
    o.w = (unsigned)v[6] | ((unsigned)v[7] << 16);
    ((uint4*)dst)[idx] = o;
}

// Z^T pass: acc[nt][mt] += A(weights, global) @ B(h rows, LDS), K=224.
// ALL 35 A-fragment loads + 14 LDS loads issued up front -> deep MLP,
// then the MFMA consume loop drains them with fine-grained waitcnt.
__device__ __forceinline__ void gemm_pass(f32x4 (&acc)[2][CTPW],
                                          const ushort* __restrict__ hrow,
                                          const ushort* __restrict__ bmat,
                                          int lane, int ct0) {
    const int l15 = lane & 15, q = lane >> 4;
    s16x8 af[KB][CTPW];
    s16x8 bh[KB][2];
    const ushort* ap = bmat + (size_t)(ct0 * 64 + lane) * 8;
#pragma unroll
    for (int kb = 0; kb < KB; ++kb) {
        const ushort* ak = ap + (size_t)kb * (NT * 64 * 8);
#pragma unroll
        for (int mt = 0; mt < CTPW; ++mt)
            af[kb][mt] = *(const s16x8*)(ak + (size_t)mt * 64 * 8);
    }
    const ushort* b0p = hrow + l15 * HS + q * 8;
    const ushort* b1p = hrow + (16 + l15) * HS + q * 8;
#pragma unroll
    for (int kb = 0; kb < KB; ++kb) {
        bh[kb][0] = *(const s16x8*)(b0p + kb * 32);
        bh[kb][1] = *(const s16x8*)(b1p + kb * 32);
    }
#pragma unroll
    for (int kb = 0; kb < KB; ++kb) {
#pragma unroll
        for (int mt = 0; mt < CTPW; ++mt) {
            acc[0][mt] = __builtin_amdgcn_mfma_f32_16x16x32_bf16(af[kb][mt], bh[kb][0], acc[0][mt], 0, 0, 0);
            acc[1][mt] = __builtin_amdgcn_mfma_f32_16x16x32_bf16(af[kb][mt], bh[kb][1], acc[1][mt], 0, 0, 0);
        }
    }
}

// lane-local cell update: acc[nt][mt] regs r=0..3 are gates i,f,g,o of
// unit u=(ct0+mt)*4+q, batch n=nt*16+l15. No shuffles. Writes new h (bf16).
__device__ __forceinline__ void gate_phase(f32x4 (&acc)[2][CTPW],
                                           float (&creg)[2][CTPW],
                                           ushort (*hbl)[HS],
                                           int lane, int ct0) {
    const int l15 = lane & 15, q = lane >> 4;
#pragma unroll
    for (int nt = 0; nt < 2; ++nt) {
#pragma unroll
        for (int mt = 0; mt < CTPW; ++mt) {
            const int u = (ct0 + mt) * 4 + q;
            const int n = nt * 16 + l15;
            f32x4 z = acc[nt][mt];
            float iv = sigmoid_fast(z[0]);
            float fv = sigmoid_fast(z[1]);
            float gv = tanh_fast(z[2]);
            float ov = sigmoid_fast(z[3]);
            float c = fv * creg[nt][mt] + iv * gv;
            creg[nt][mt] = c;
            hbl[n][u] = f2bf(ov * tanh_fast(c));
        }
    }
}

__global__ void __launch_bounds__(THREADS, 2)
lstm3_mfma(const float* __restrict__ x,
           const float* __restrict__ W0, const float* __restrict__ b0,
           const float* __restrict__ b1, const float* __restrict__ b2,
           const float* __restrict__ Wfc, const float* __restrict__ bfc,
           const ushort* __restrict__ packed,
           float* __restrict__ out) {
    __shared__ ushort hb[3][BT][HS];   // h state, bf16, rows = batch (44.5 KB)
    __shared__ float  xT[Tlen][BT];    // x transposed (12.8 KB)
    __shared__ float  pbw[4][NP];      // permuted b0,b1,b2,W0 (12.8 KB)

    const int tid = threadIdx.x;
    const int wave = tid >> 6, lane = tid & 63;
    const int l15 = lane & 15, q = lane >> 4;
    const int ct0 = wave * CTPW;       // M-tile base
    const int bbase = blockIdx.x * BT;

    for (int i = tid; i < 3 * BT * HS; i += THREADS) ((ushort*)hb)[i] = 0;
    for (int i = tid; i < BT * Tlen; i += THREADS) {
        int m = i / Tlen, t = i % Tlen;
        xT[t][m] = x[(size_t)(bbase + m) * Tlen + t];
    }
    for (int i = tid; i < NP; i += THREADS) {
        int nc = (i & 3) * Hdim + (i >> 2);   // permuted col -> src col
        pbw[0][i] = b0[nc]; pbw[1][i] = b1[nc]; pbw[2][i] = b2[nc]; pbw[3][i] = W0[nc];
    }
    __syncthreads();

    float creg[3][2][CTPW];   // c state: 30 regs, static (layer, nt, mt) mapping
#pragma unroll
    for (int l = 0; l < 3; ++l)
#pragma unroll
        for (int nt = 0; nt < 2; ++nt)
#pragma unroll
            for (int mt = 0; mt < CTPW; ++mt) creg[l][nt][mt] = 0.0f;

    const ushort* pU0 = packed;
    const ushort* pW1 = packed + (size_t)MATSZ;
    const ushort* pU1 = packed + (size_t)2 * MATSZ;
    const ushort* pW2 = packed + (size_t)3 * MATSZ;
    const ushort* pU2 = packed + (size_t)4 * MATSZ;

    for (int t = 0; t < Tlen; ++t) {
        f32x4 acc[2][CTPW];

        // ---- layer 0: Z^T = b0 + W0^T x_t + U0^T h0 ----
        const float xn0 = xT[t][l15];
        const float xn1 = xT[t][16 + l15];
#pragma unroll
        for (int mt = 0; mt < CTPW; ++mt) {
            const int row = (ct0 + mt) * 16 + q * 4;
            float4 bb = *(const float4*)&pbw[0][row];
            float4 ww = *(const float4*)&pbw[3][row];
            acc[0][mt][0] = fmaf(xn0, ww.x, bb.x); acc[1][mt][0] = fmaf(xn1, ww.x, bb.x);
            acc[0][mt][1] = fmaf(xn0, ww.y, bb.y); acc[1][mt][1] = fmaf(xn1, ww.y, bb.y);
            acc[0][mt][2] = fmaf(xn0, ww.z, bb.z); acc[1][mt][2] = fmaf(xn1, ww.z, bb.z);
            acc[0][mt][3] = fmaf(xn0, ww.w, bb.w); acc[1][mt][3] = fmaf(xn1, ww.w, bb.w);
        }
        gemm_pass(acc, &hb[0][0][0], pU0, lane, ct0);
        __syncthreads();                               // all reads of old h0 done
        gate_phase(acc, creg[0], hb[0], lane, ct0);    // write new h0
        __syncthreads();

        // ---- layer 1: Z^T = b1 + W1^T h0new + U1^T h1 ----
#pragma unroll
        for (int mt = 0; mt < CTPW; ++mt) {
            const int row = (ct0 + mt) * 16 + q * 4;
            float4 bb = *(const float4*)&pbw[1][row];
#pragma unroll
            for (int r = 0; r < 4; ++r) {
                float v = (r == 0) ? bb.x : (r == 1) ? bb.y : (r == 2) ? bb.z : bb.w;
                acc[0][mt][r] = v; acc[1][mt][r] = v;
            }
        }
        gemm_pass(acc, &hb[0][0][0], pW1, lane, ct0);
        gemm_pass(acc, &hb[1][0][0], pU1, lane, ct0);
        __syncthreads();
        gate_phase(acc, creg[1], hb[1], lane, ct0);
        __syncthreads();

        // ---- layer 2: Z^T = b2 + W2^T h1new + U2^T h2 ----
#pragma unroll
        for (int mt = 0; mt < CTPW; ++mt) {
            const int row = (ct0 + mt) * 16 + q * 4;
            float4 bb = *(const float4*)&pbw[2][row];
#pragma unroll
            for (int r = 0; r < 4; ++r) {
                float v = (r == 0) ? bb.x : (r == 1) ? bb.y : (r == 2) ? bb.z : bb.w;
                acc[0][mt][r] = v; acc[1][mt][r] = v;
            }
        }
        gemm_pass(acc, &hb[1][0][0], pW2, lane, ct0);
        gemm_pass(acc, &hb[2][0][0], pU2, lane, ct0);
        __syncthreads();
        gate_phase(acc, creg[2], hb[2], lane, ct0);
        __syncthreads();
    }

    // ---- dense head: y = tanh(h2 @ Wfc + bfc); contiguous float4 stores ----
    for (int gidx = tid; gidx < BT * 100; gidx += THREADS) {
        int m = gidx / 100;
        int j4 = (gidx % 100) * 4;
        const ushort* h2 = &hb[2][m][0];
        float4 a4 = *(const float4*)(bfc + j4);
        float s0 = a4.x, s1 = a4.y, s2 = a4.z, s3 = a4.w;
        for (int k = 0; k < Hdim; ++k) {
            float hk = bf2f(h2[k]);
            float4 w4 = *(const float4*)(Wfc + (size_t)k * 400 + j4);
            s0 = fmaf(hk, w4.x, s0);
            s1 = fmaf(hk, w4.y, s1);
            s2 = fmaf(hk, w4.z, s2);
            s3 = fmaf(hk, w4.w, s3);
        }
        float4 o4;
        o4.x = tanh_fast(s0); o4.y = tanh_fast(s1);
        o4.z = tanh_fast(s2); o4.w = tanh_fast(s3);
        *(float4*)(out + (size_t)(bbase + m) * 400 + j4) = o4;
    }
}

extern "C" void kernel_launch(void* const* d_in, const int* in_sizes, int n_in,
                              void* d_out, int out_size, void* d_ws, size_t ws_size,
                              hipStream_t stream) {
    const float* x   = (const float*)d_in[0];
    const float* W0  = (const float*)d_in[1];
    const float* U0  = (const float*)d_in[2];
    const float* b0  = (const float*)d_in[3];
    const float* W1  = (const float*)d_in[4];
    const float* U1  = (const float*)d_in[5];
    const float* b1  = (const float*)d_in[6];
    const float* W2  = (const float*)d_in[7];
    const float* U2  = (const float*)d_in[8];
    const float* b2  = (const float*)d_in[9];
    const float* Wfc = (const float*)d_in[10];
    const float* bfc = (const float*)d_in[11];
    float* out = (float*)d_out;
    ushort* packed = (ushort*)d_ws;

    const int B = in_sizes[0] / Tlen;   // 8192
    const int pack_threads = 5 * KB * NT * 64;
    pack_weights<<<(pack_threads + 255) / 256, 256, 0, stream>>>(U0, W1, U1, W2, U2, packed);
    lstm3_mfma<<<B / BT, THREADS, 0, stream>>>(x, W0, b0, b1, b2, Wfc, bfc, packed, out);
}

// Round 6
// 9198.741 us; speedup vs baseline: 1.3882x; 1.0724x over previous
//
#include <hip/hip_runtime.h>

#define Hdim 200
#define NP   800
#define Tlen 100
#define BT   32          // batch rows per WG -> grid = 256 = 1 WG/CU
#define KB   7           // K blocks of 32 (200 -> 224 padded)
#define HS   232         // padded h row stride (ushorts): 2-way bank alias = free
#define NT   50          // 800/16 gate-col tiles (M dimension of Z^T)
#define THREADS 640      // 10 waves x 5 M-tiles each
#define CH   5           // M-tiles per wave
#define CHSTR (NT*64*8)  // ushorts per K-chunk (25600)
#define MATSZ (KB*CHSTR) // 179200 ushorts per packed matrix

typedef float f32x4 __attribute__((ext_vector_type(4)));
typedef short s16x8 __attribute__((ext_vector_type(8)));

__device__ __forceinline__ ushort f2bf(float f) {
    unsigned u = __float_as_uint(f);
    return (ushort)((u + 0x7fffu + ((u >> 16) & 1u)) >> 16);   // RTNE
}
__device__ __forceinline__ float bf2f(ushort s) {
    return __uint_as_float(((unsigned)s) << 16);
}
__device__ __forceinline__ float sigmoid_fast(float v) {
    return 1.0f / (1.0f + __expf(-v));
}
__device__ __forceinline__ float tanh_fast(float v) {
    return 2.0f / (1.0f + __expf(-2.0f * v)) - 1.0f;
}

// ---- pack 5 recurrent matrices [200][800] fp32 -> bf16 fragment layout ----
// slot (mi, kb, tile, lane, j) = W[k = kb*32 + (lane>>4)*8 + j][n' = tile*16 + (lane&15)]
// gate-interleaved cols: n' = unit*4 + gate -> src col = gate*200 + unit. k>=200 -> 0.
__global__ void pack_weights(const float* __restrict__ U0, const float* __restrict__ W1,
                             const float* __restrict__ U1, const float* __restrict__ W2,
                             const float* __restrict__ U2, ushort* __restrict__ dst) {
    int idx = blockIdx.x * blockDim.x + threadIdx.x;
    if (idx >= 5 * KB * NT * 64) return;
    int lane = idx & 63; int rest = idx >> 6;
    int nt = rest % NT; rest /= NT;
    int kb = rest % KB; int mi = rest / KB;
    const float* src = (mi == 0) ? U0 : (mi == 1) ? W1 : (mi == 2) ? U1 : (mi == 3) ? W2 : U2;
    int np = nt * 16 + (lane & 15);
    int ncol = (np & 3) * Hdim + (np >> 2);          // gate*200 + unit
    int k0 = kb * 32 + (lane >> 4) * 8;
    ushort v[8];
#pragma unroll
    for (int j = 0; j < 8; ++j) {
        int k = k0 + j;
        v[j] = (k < Hdim) ? f2bf(src[k * NP + ncol]) : (ushort)0;
    }
    uint4 o;
    o.x = (unsigned)v[0] | ((unsigned)v[1] << 16);
    o.y = (unsigned)v[2] | ((unsigned)v[3] << 16);
    o.z = (unsigned)v[4] | ((unsigned)v[5] << 16);
    o.w = (unsigned)v[6] | ((unsigned)v[7] << 16);
    ((uint4*)dst)[idx] = o;
}

// Software-pipelined region of NC K-chunks (NC=7: single matrix; NC=14: U then W).
// af: triple-buffered global fragment prefetch (2-chunk lookahead, 10 loads in
// flight per wave). bh: double-buffered LDS reads. All indices compile-time.
// apU/apW pre-offset by (ct0*64+lane)*8; bU/bW pre-offset by l15*HS + q*8.
template<int NC>
__device__ __forceinline__ void gemm_region(f32x4 (&acc)[2][CH],
                                            const ushort* __restrict__ apU,
                                            const ushort* bU,
                                            const ushort* __restrict__ apW,
                                            const ushort* bW) {
    s16x8 af[3][CH];
    s16x8 bh[2][2];
#pragma unroll
    for (int p = 0; p < 2; ++p) {
        const ushort* a = (p < KB) ? (apU + (size_t)p * CHSTR) : (apW + (size_t)(p - KB) * CHSTR);
#pragma unroll
        for (int mt = 0; mt < CH; ++mt)
            af[p][mt] = *(const s16x8*)(a + (size_t)mt * 512);
    }
    bh[0][0] = *(const s16x8*)(bU);
    bh[0][1] = *(const s16x8*)(bU + 16 * HS);
#pragma unroll
    for (int c = 0; c < NC; ++c) {
        if (c + 2 < NC) {
            const int p = c + 2;
            const ushort* a = (p < KB) ? (apU + (size_t)p * CHSTR) : (apW + (size_t)(p - KB) * CHSTR);
#pragma unroll
            for (int mt = 0; mt < CH; ++mt)
                af[p % 3][mt] = *(const s16x8*)(a + (size_t)mt * 512);
        }
        if (c + 1 < NC) {
            const int p = c + 1;
            const ushort* b = (p < KB) ? (bU + p * 32) : (bW + (p - KB) * 32);
            bh[p & 1][0] = *(const s16x8*)(b);
            bh[p & 1][1] = *(const s16x8*)(b + 16 * HS);
        }
#pragma unroll
        for (int mt = 0; mt < CH; ++mt) {
            acc[0][mt] = __builtin_amdgcn_mfma_f32_16x16x32_bf16(af[c % 3][mt], bh[c & 1][0], acc[0][mt], 0, 0, 0);
            acc[1][mt] = __builtin_amdgcn_mfma_f32_16x16x32_bf16(af[c % 3][mt], bh[c & 1][1], acc[1][mt], 0, 0, 0);
        }
    }
}

// lane-local cell update: acc[nt][mt] regs r=0..3 are gates i,f,g,o of
// unit u=(ct0+mt)*4+q, batch n=nt*16+l15. Writes new h (bf16) to dst buffer.
__device__ __forceinline__ void gate_phase(f32x4 (&acc)[2][CH],
                                           float (&creg)[2][CH],
                                           ushort (*hbl)[HS],
                                           int lane, int ct0) {
    const int l15 = lane & 15, q = lane >> 4;
#pragma unroll
    for (int nt = 0; nt < 2; ++nt) {
#pragma unroll
        for (int mt = 0; mt < CH; ++mt) {
            const int u = (ct0 + mt) * 4 + q;
            const int n = nt * 16 + l15;
            f32x4 z = acc[nt][mt];
            float iv = sigmoid_fast(z[0]);
            float fv = sigmoid_fast(z[1]);
            float gv = tanh_fast(z[2]);
            float ov = sigmoid_fast(z[3]);
            float c = fv * creg[nt][mt] + iv * gv;
            creg[nt][mt] = c;
            hbl[n][u] = f2bf(ov * tanh_fast(c));
        }
    }
}

__global__ void __launch_bounds__(THREADS)
__attribute__((amdgpu_waves_per_eu(2, 3)))
lstm3_mfma(const float* __restrict__ x,
           const float* __restrict__ W0, const float* __restrict__ b0,
           const float* __restrict__ b1, const float* __restrict__ b2,
           const float* __restrict__ Wfc, const float* __restrict__ bfc,
           const ushort* __restrict__ packed,
           float* __restrict__ out) {
    __shared__ ushort hb[2][3][BT][HS];  // ping-pong h state, bf16 (89 KB)
    __shared__ float  xT[Tlen][BT];      // x transposed (12.8 KB)
    __shared__ float  pbw[4][NP];        // permuted b0,b1,b2,W0 (12.8 KB)

    const int tid = threadIdx.x;
    const int wave = tid >> 6, lane = tid & 63;
    const int l15 = lane & 15, q = lane >> 4;
    const int ct0 = wave * CH;           // M-tile base
    const int bbase = blockIdx.x * BT;

    for (int i = tid; i < 2 * 3 * BT * HS; i += THREADS) ((ushort*)hb)[i] = 0;
    for (int i = tid; i < BT * Tlen; i += THREADS) {
        int m = i / Tlen, t = i % Tlen;
        xT[t][m] = x[(size_t)(bbase + m) * Tlen + t];
    }
    for (int i = tid; i < NP; i += THREADS) {
        int nc = (i & 3) * Hdim + (i >> 2);   // permuted col -> src col
        pbw[0][i] = b0[nc]; pbw[1][i] = b1[nc]; pbw[2][i] = b2[nc]; pbw[3][i] = W0[nc];
    }
    __syncthreads();

    float creg[3][2][CH];   // c state: 30 regs, static mapping
#pragma unroll
    for (int l = 0; l < 3; ++l)
#pragma unroll
        for (int nt = 0; nt < 2; ++nt)
#pragma unroll
            for (int mt = 0; mt < CH; ++mt) creg[l][nt][mt] = 0.0f;

    const size_t fragoff = (size_t)(ct0 * 64 + lane) * 8;
    const ushort* pU0 = packed + fragoff;
    const ushort* pW1 = packed + (size_t)MATSZ + fragoff;
    const ushort* pU1 = packed + (size_t)2 * MATSZ + fragoff;
    const ushort* pW2 = packed + (size_t)3 * MATSZ + fragoff;
    const ushort* pU2 = packed + (size_t)4 * MATSZ + fragoff;
    const int bhoff = l15 * HS + q * 8;

    for (int t = 0; t < Tlen; ++t) {
        const int cr = t & 1, nx = cr ^ 1;
        f32x4 acc[2][CH];

        // ---- layer 0: Z^T = b0 + W0^T x_t + U0^T h0[cr] -> h0[nx] ----
        const float xn0 = xT[t][l15];
        const float xn1 = xT[t][16 + l15];
#pragma unroll
        for (int mt = 0; mt < CH; ++mt) {
            const int row = (ct0 + mt) * 16 + q * 4;
            float4 bb = *(const float4*)&pbw[0][row];
            float4 ww = *(const float4*)&pbw[3][row];
            acc[0][mt][0] = fmaf(xn0, ww.x, bb.x); acc[1][mt][0] = fmaf(xn1, ww.x, bb.x);
            acc[0][mt][1] = fmaf(xn0, ww.y, bb.y); acc[1][mt][1] = fmaf(xn1, ww.y, bb.y);
            acc[0][mt][2] = fmaf(xn0, ww.z, bb.z); acc[1][mt][2] = fmaf(xn1, ww.z, bb.z);
            acc[0][mt][3] = fmaf(xn0, ww.w, bb.w); acc[1][mt][3] = fmaf(xn1, ww.w, bb.w);
        }
        gemm_region<KB>(acc, pU0, &hb[cr][0][0][0] + bhoff, pU0, &hb[cr][0][0][0] + bhoff);
        gate_phase(acc, creg[0], hb[nx][0], lane, ct0);
        __syncthreads();   // BAR_A: new h0 visible; old-h0 reads done

        // ---- layer 1: Z^T = b1 + U1^T h1[cr] + W1^T h0[nx] -> h1[nx] ----
#pragma unroll
        for (int mt = 0; mt < CH; ++mt) {
            const int row = (ct0 + mt) * 16 + q * 4;
            float4 bb = *(const float4*)&pbw[1][row];
            acc[0][mt][0] = bb.x; acc[1][mt][0] = bb.x;
            acc[0][mt][1] = bb.y; acc[1][mt][1] = bb.y;
            acc[0][mt][2] = bb.z; acc[1][mt][2] = bb.z;
            acc[0][mt][3] = bb.w; acc[1][mt][3] = bb.w;
        }
        gemm_region<2 * KB>(acc, pU1, &hb[cr][1][0][0] + bhoff, pW1, &hb[nx][0][0][0] + bhoff);
        gate_phase(acc, creg[1], hb[nx][1], lane, ct0);
        __syncthreads();   // BAR_B: new h1 visible; old-h1 reads done

        // ---- layer 2: Z^T = b2 + U2^T h2[cr] + W2^T h1[nx] -> h2[nx] ----
#pragma unroll
        for (int mt = 0; mt < CH; ++mt) {
            const int row = (ct0 + mt) * 16 + q * 4;
            float4 bb = *(const float4*)&pbw[2][row];
            acc[0][mt][0] = bb.x; acc[1][mt][0] = bb.x;
            acc[0][mt][1] = bb.y; acc[1][mt][1] = bb.y;
            acc[0][mt][2] = bb.z; acc[1][mt][2] = bb.z;
            acc[0][mt][3] = bb.w; acc[1][mt][3] = bb.w;
        }
        gemm_region<2 * KB>(acc, pU2, &hb[cr][2][0][0] + bhoff, pW2, &hb[nx][1][0][0] + bhoff);
        gate_phase(acc, creg[2], hb[nx][2], lane, ct0);
        // no barrier needed here: next-t hazards are covered by BAR_A/BAR_B(t+1)
    }
    __syncthreads();       // h2 final visible to all threads for the head

    // ---- dense head: y = tanh(h2 @ Wfc + bfc); final h2 is in buffer 0 ----
    for (int gidx = tid; gidx < BT * 100; gidx += THREADS) {
        int m = gidx / 100;
        int j4 = (gidx % 100) * 4;
        const ushort* h2 = &hb[Tlen & 1][2][m][0];
        float4 a4 = *(const float4*)(bfc + j4);
        float s0 = a4.x, s1 = a4.y, s2 = a4.z, s3 = a4.w;
        for (int k = 0; k < Hdim; ++k) {
            float hk = bf2f(h2[k]);
            float4 w4 = *(const float4*)(Wfc + (size_t)k * 400 + j4);
            s0 = fmaf(hk, w4.x, s0);
            s1 = fmaf(hk, w4.y, s1);
            s2 = fmaf(hk, w4.z, s2);
            s3 = fmaf(hk, w4.w, s3);
        }
        float4 o4;
        o4.x = tanh_fast(s0); o4.y = tanh_fast(s1);
        o4.z = tanh_fast(s2); o4.w = tanh_fast(s3);
        *(float4*)(out + (size_t)(bbase + m) * 400 + j4) = o4;
    }
}

extern "C" void kernel_launch(void* const* d_in, const int* in_sizes, int n_in,
                              void* d_out, int out_size, void* d_ws, size_t ws_size,
                              hipStream_t stream) {
    const float* x   = (const float*)d_in[0];
    const float* W0  = (const float*)d_in[1];
    const float* U0  = (const float*)d_in[2];
    const float* b0  = (const float*)d_in[3];
    const float* W1  = (const float*)d_in[4];
    const float* U1  = (const float*)d_in[5];
    const float* b1  = (const float*)d_in[6];
    const float* W2  = (const float*)d_in[7];
    const float* U2  = (const float*)d_in[8];
    const float* b2  = (const float*)d_in[9];
    const float* Wfc = (const float*)d_in[10];
    const float* bfc = (const float*)d_in[11];
    float* out = (float*)d_out;
    ushort* packed = (ushort*)d_ws;

    const int B = in_sizes[0] / Tlen;   // 8192
    const int pack_threads = 5 * KB * NT * 64;
    pack_weights<<<(pack_threads + 255) / 256, 256, 0, stream>>>(U0, W1, U1, W2, U2, packed);
    lstm3_mfma<<<B / BT, THREADS, 0, stream>>>(x, W0, b0, b1, b2, Wfc, bfc, packed, out);
}